// Round 3
// baseline (1815.446 us; speedup 1.0000x reference)
//
#include <hip/hip_runtime.h>
#include <hip/hip_bf16.h>
#include <math.h>

typedef __hip_bfloat16 bf16;
#define DEV static __device__ __forceinline__
DEV float b2f(bf16 x){ return __bfloat162float(x); }
DEV bf16  f2b(float x){ return __float2bfloat16(x); }
DEV float blo(unsigned int w){ return __uint_as_float(w<<16); }
DEV float bhi(unsigned int w){ return __uint_as_float(w&0xffff0000u); }
DEV float ldin(const void* p, long i, int f){
  return f ? ((const float*)p)[i] : b2f(((const bf16*)p)[i]);
}

// problem dims
#define PP 25088            // t*h*w = 8*56*56

// ws layout (float units)
#define X1o    0L           // 2*64*25088
#define POOLo  3211264L     // 2*588*64   [b][m][c]
#define XW1o   3286528L     // 2*588*64   [b][m][c]
#define WXo    3361792L     // 2*13*125*64
#define WXTo   3569792L     // 2*125*64*16 (o padded 13->16, o inner)
#define WIXo   3825792L     // 2*64*49    [b][c][kk]
#define ATTo   3832064L     // 2*13*25088 (post-sigmoid)
#define KERNo  4484352L     // 2*49*25088
#define XW3o   6942976L     // 2*16*12*3136
#define STATo  8147200L     // sums(1024) + scale/shift(1024)
#define FLAGo  8149248L     // dtype flag (int), 16 floats reserved
#define WFo    8149264L     // converted f32 weights (118016)
#define WATTFo 8267280L     // W_att as f32 (955500, pad 955504)
#define WINVFo 9222784L     // W_inv as f32 (28812, pad 28816)
#define BF16o  9251600L     // bf16 region starts here (float idx)
// wf sub-offsets
#define oWCT   0            // [ci][co] 64x64
#define oBCT   4096
#define oWWSI  4160         // [co][ci] (untransposed)
#define oBWSI  8256
#define oWRR   8320         // [(ci*27+tap)*16+co]
#define oBINV  35968
#define oWP1   36032        // [ci][co] 256x256
#define oWP2   101568       // [ci][co] 256x64
#define oBP2   117952
// bf16 sub-offsets (bf16 element units)
#define bXCT   0L           // 3211264
#define bXWSI  3211264L     // 4816896
#define bXATT  8028160L     // 12845056
#define bY1    20873216L    // 12845056
#define bINV   20873216L    // alias: y1 dead after k_bn1
#define bXATT1 33718272L    // 12845056

// ---- input dtype probe: even uint16s of an f32 buffer are mantissa garbage ----
__global__ void k_detect(const unsigned short* raw, int* flag){
  int t = threadIdx.x;                       // 64 lanes
  unsigned short u = raw[2*t];               // low half of f32 word t (if f32)
  int e = (u>>7)&0xFF;
  int hit = (e >= 137);                      // |bf16| >= 1024 or inf/nan: impossible for N(0,1) bf16
  unsigned long long m = __ballot(hit);
  if(t==0) flag[0] = (__popcll(m) >= 8) ? 1 : 0;   // 1 = inputs are f32
}

// ---- canonicalize inputs ----
__global__ void k_c2b(const void* src, bf16* dst, int n, const int* flag){
  int i = blockIdx.x*256+threadIdx.x; if(i>=n) return;
  int f = flag[0];
  dst[i] = f ? f2b(((const float*)src)[i]) : ((const bf16*)src)[i];
}
__global__ void k_c2f(const void* src, float* dst, int n, const int* flag){
  int i = blockIdx.x*256+threadIdx.x; if(i>=n) return;
  dst[i] = ldin(src, i, flag[0]);
}

// ---- weight convert (+transpose to put out-channel innermost) ----
__global__ void k_cvt(const void* Wct,const void* bct,const void* Wwsi,const void* bwsi,
                      const void* Wrr,const void* binv,const void* Wp1,const void* Wp2,
                      const void* bp2,float* wf,const int* flag){
  int i = blockIdx.x*256 + threadIdx.x;
  int f = flag[0];
  if (i < 4096){ int co=i>>6, ci=i&63; wf[oWCT + ci*64+co] = ldin(Wct,i,f); }
  else if (i < 4160){ wf[i] = ldin(bct,i-4096,f); }
  else if (i < 8256){ wf[i] = ldin(Wwsi,i-4160,f); }
  else if (i < 8320){ wf[i] = ldin(bwsi,i-8256,f); }
  else if (i < 35968){ int l=i-8320; int co=l/1728, r=l%1728, ci=r/27, tp=r%27;
                       wf[oWRR + (ci*27+tp)*16+co] = ldin(Wrr,l,f); }
  else if (i < 36017){ wf[oBINV + (i-35968)] = ldin(binv,i-35968,f); }
  else if (i < 36032){ }
  else if (i < 101568){ int l=i-36032; int co=l>>8, ci=l&255; wf[oWP1 + ci*256+co] = ldin(Wp1,l,f); }
  else if (i < 117952){ int l=i-101568; int o=l>>8, ci=l&255; wf[oWP2 + ci*64+o] = ldin(Wp2,l,f); }
  else if (i < 118016){ int l=i-117952; if(l<64) wf[oBP2 + l] = ldin(bp2,l,f); }
}

// ---- adaptive pool of raw x_WSI (pool commutes with 1x1 conv) ----
__global__ void k_pool(const bf16* xwsi, float* pool){
  int i = blockIdx.x*256+threadIdx.x;            // 75264 = 2*588*64
  int c = i&63; int m=(i>>6)%588; int b=i/37632;
  int d=m/49, r=m%49, ii=r/7, jj=r%7;
  const bf16* src = xwsi + ((size_t)(b*64+c)*12 + d)*3136 + (ii*8)*56 + jj*8;
  float s=0;
  for(int u=0;u<8;u++) for(int v=0;v<8;v++) s += b2f(src[u*56+v]);
  pool[i] = s*(1.f/64.f);
}

// ---- xw1 = W_wsi * pooled + b ; layout [b][m][c] ----
__global__ void k_xw1(const float* pool, const float* wf, float* xw1){
  int i = blockIdx.x*256+threadIdx.x;
  int c = i&63; int m=(i>>6)%588; int b=i/37632;
  const float* p = pool + (b*588+m)*64;
  const float* w = wf + oWWSI + c*64;
  float s = wf[oBWSI + c];
  for(int ci=0;ci<64;ci++) s += w[ci]*p[ci];
  xw1[i]=s;
}

// ---- Wx[b,o,tap,c] = sum_m W_att[o,m,tap] * xw1[b,c,m] ----
__global__ void k_Wx(const float* Wattf, const float* xw1, float* Wx){
  int i = blockIdx.x*256+threadIdx.x; if(i>=208000) return;
  int c=i&63; int r=i>>6; int tap=r%125; int o=(r/125)%13; int b=r/1625;
  const float* wa = Wattf + (size_t)o*588*125 + tap;
  const float* xp = xw1 + b*588*64 + c;
  float s=0;
  for(int m=0;m<588;m++) s += wa[(size_t)m*125] * xp[m*64];
  Wx[i]=s;
}
__global__ void k_WxT(const float* Wx, float* WxT){
  int i = blockIdx.x*256+threadIdx.x; if(i>=256000) return;
  int o=i&15; int c=(i>>4)&63; int tap=(i>>10)%125; int b=i/128000;
  WxT[i] = (o<13) ? Wx[((b*13+o)*125+tap)*64+c] : 0.f;
}

// ---- Winvx[b][c][kk] = sum_m W_inv[kk,m] * xw1[b,c,m] ----
__global__ void k_Winvx(const float* Winvf, const float* xw1, float* Wix){
  int i = blockIdx.x*256+threadIdx.x; if(i>=6272) return;
  int kk=i%49; int c=(i/49)&63; int b=i/3136;
  const float* xp = xw1 + b*588*64 + c;
  float s=0;
  for(int m=0;m<588;m++) s += Winvf[kk*588+m] * xp[m*64];
  Wix[i]=s;
}

// ---- x1 = W_ct * x_CT + b (f32) ----
__global__ void k_x1(const bf16* xct, const float* wf, float* x1){
  int p = blockIdx.x*256+threadIdx.x;
  int co0 = blockIdx.y*16; int b = blockIdx.z;
  float acc[16];
  #pragma unroll
  for(int o=0;o<16;o++) acc[o]=wf[oBCT+co0+o];
  const bf16* xp = xct + (size_t)b*64*PP + p;
  for(int ci=0;ci<64;ci++){
    float xv = b2f(xp[(size_t)ci*PP]);
    const float* w = wf + oWCT + ci*64 + co0;
    #pragma unroll
    for(int o=0;o<16;o++) acc[o] += w[o]*xv;
  }
  float* out = x1 + ((size_t)b*64+co0)*PP + p;
  #pragma unroll
  for(int o=0;o<16;o++) out[(size_t)o*PP]=acc[o];
}

// ---- Att = sigmoid(conv5x5x5(x1, Wx))  (the big one) ----
__global__ __launch_bounds__(256) void k_att(const float* x1, const float* WxT, float* att){
  __shared__ float xt[16][20][20];
  int tid=threadIdx.x;
  int bx=blockIdx.x, t=blockIdx.y, b=blockIdx.z;
  int y0=(bx>>2)*16, x0=(bx&3)*16;
  int ty=tid>>4, tx=tid&15;
  float acc[13];
  #pragma unroll
  for(int o=0;o<13;o++) acc[o]=0;
  for(int dt=0;dt<5;dt++){
    int ti=t+dt-2; if(ti<0||ti>=8) continue;
    for(int c0=0;c0<64;c0+=16){
      __syncthreads();
      for(int e=tid;e<6400;e+=256){
        int c=e/400, rm=e%400, yy=rm/20, xx=rm%20;
        int gy=y0+yy-2, gx=x0+xx-2;
        float v=0;
        if(gy>=0&&gy<56&&gx>=0&&gx<56)
          v = x1[((size_t)(b*64+c0+c)*8+ti)*3136 + gy*56+gx];
        xt[c][yy][xx]=v;
      }
      __syncthreads();
      const float* wb = WxT + ((size_t)(b*125 + dt*25)*64 + c0)*16;
      for(int c=0;c<16;c++){
        for(int dy=0;dy<5;dy++){
          #pragma unroll
          for(int dx=0;dx<5;dx++){
            float xv = xt[c][ty+dy][tx+dx];
            const float* wp = wb + ((dy*5+dx)*64 + c)*16;
            #pragma unroll
            for(int o=0;o<13;o++) acc[o] += wp[o]*xv;
          }
        }
      }
    }
  }
  int gy=y0+ty, gx=x0+tx;
  if(gy<56&&gx<56){
    size_t p=(size_t)t*3136+gy*56+gx;
    #pragma unroll
    for(int o=0;o<13;o++)
      att[((size_t)b*13+o)*PP+p] = 1.f/(1.f+__expf(-acc[o]));
  }
}

// ---- kern49 = Winvx * x1 + b_inv ----
__global__ void k_kern(const float* x1, const float* Wix, const float* wf, float* kern){
  int p = blockIdx.x*256+threadIdx.x; int b=blockIdx.y;
  float acc[49];
  #pragma unroll
  for(int kk=0;kk<49;kk++) acc[kk]=wf[oBINV+kk];
  const float* xp = x1 + (size_t)b*64*PP + p;
  for(int c=0;c<64;c++){
    float xv = xp[(size_t)c*PP];
    const float* w = Wix + (b*64+c)*49;
    #pragma unroll
    for(int kk=0;kk<49;kk++) acc[kk]+=w[kk]*xv;
  }
  float* out = kern + (size_t)b*49*PP + p;
  #pragma unroll
  for(int kk=0;kk<49;kk++) out[(size_t)kk*PP]=acc[kk];
}

// ---- xw3 = conv3x3x3(x_WSI, W_rr, pad=1) ----
__global__ __launch_bounds__(64) void k_rr(const bf16* xwsi, const float* wf, float* xw3){
  __shared__ float xt[16][10][10];
  int tid=threadIdx.x; int bx=blockIdx.x, d=blockIdx.y, b=blockIdx.z;
  int y0=(bx/7)*8, x0=(bx%7)*8;
  int ty=tid>>3, tx=tid&7;
  float acc[16];
  #pragma unroll
  for(int o=0;o<16;o++) acc[o]=0;
  for(int dz=0;dz<3;dz++){
    int di=d+dz-1; if(di<0||di>=12) continue;
    for(int c0=0;c0<64;c0+=16){
      __syncthreads();
      for(int e=tid;e<1600;e+=64){
        int c=e/100, rm=e%100, yy=rm/10, xx=rm%10;
        int gy=y0+yy-1, gx=x0+xx-1;
        float v=0;
        if(gy>=0&&gy<56&&gx>=0&&gx<56)
          v=b2f(xwsi[((size_t)(b*64+c0+c)*12+di)*3136+gy*56+gx]);
        xt[c][yy][xx]=v;
      }
      __syncthreads();
      for(int c=0;c<16;c++){
        #pragma unroll
        for(int dy=0;dy<3;dy++){
          #pragma unroll
          for(int dx=0;dx<3;dx++){
            float xv=xt[c][ty+dy][tx+dx];
            const float* w = wf + oWRR + ((c0+c)*27 + dz*9+dy*3+dx)*16;
            #pragma unroll
            for(int o=0;o<16;o++) acc[o]+=w[o]*xv;
          }
        }
      }
    }
  }
  float* out = xw3 + ((size_t)b*16*12 + d)*3136 + (y0+ty)*56+x0+tx;
  #pragma unroll
  for(int o=0;o<16;o++) out[(size_t)o*12*3136]=acc[o];
}

// ---- x_Att = x_FS * (1 + Att_FS)  (bf16) ----
__global__ void k_xatt(const bf16* xct, const float* xw3, const float* att, bf16* xatt){
  size_t i=(size_t)blockIdx.x*256+threadIdx.x;   // 12,845,056
  int p=(int)(i%PP); int ch=(int)((i/PP)&255); int b=(int)(i/((size_t)PP*256));
  int s=p%3136;
  float v;
  if(ch<64){
    v = b2f(xct[((size_t)b*64+ch)*PP+p]) * (1.f+att[(size_t)b*13*PP+p]);
  } else {
    int q=ch-64;
    v = xw3[((size_t)(b*16+q/12)*12 + q%12)*3136 + s] * (1.f+att[((size_t)b*13+1+q/16)*PP+p]);
  }
  xatt[i]=f2b(v);
}

// ---- y1 = W_p1 * x_Att  (b_p1 cancels in batchnorm) ----
__global__ void k_p1(const bf16* xatt, const float* wf, bf16* y1){
  int p=blockIdx.x*256+threadIdx.x;
  int co0=blockIdx.y*16; int b=blockIdx.z;
  float acc[16];
  #pragma unroll
  for(int o=0;o<16;o++) acc[o]=0;
  const bf16* xp = xatt + (size_t)b*256*PP + p;
  for(int ci=0;ci<256;ci++){
    float xv=b2f(xp[(size_t)ci*PP]);
    const float* w = wf + oWP1 + ci*256 + co0;
    #pragma unroll
    for(int o=0;o<16;o++) acc[o]+=w[o]*xv;
  }
  bf16* out = y1 + ((size_t)b*256+co0)*PP + p;
  #pragma unroll
  for(int o=0;o<16;o++) out[(size_t)o*PP]=f2b(acc[o]);
}

// ---- per-channel sum / sumsq ----
__global__ void k_stats(const bf16* src, float* sum, float* sq){
  __shared__ float rs[256], rq[256];
  int tid=threadIdx.x;
  int chunk=blockIdx.x, ch=blockIdx.y, b=blockIdx.z;
  const bf16* p = src + ((size_t)b*256+ch)*PP + chunk*3136;
  float s=0,q=0;
  for(int i=tid;i<3136;i+=256){ float v=b2f(p[i]); s+=v; q+=v*v; }
  rs[tid]=s; rq[tid]=q; __syncthreads();
  for(int st=128;st>0;st>>=1){ if(tid<st){rs[tid]+=rs[tid+st]; rq[tid]+=rq[tid+st];} __syncthreads(); }
  if(tid==0){ atomicAdd(&sum[ch],rs[0]); atomicAdd(&sq[ch],rq[0]); }
}
__global__ void k_finstat(const float* sum, const float* sq, const void* g, const void* be,
                          const int* flag, float* sc, float* sh){
  int ch=threadIdx.x;
  int f=flag[0];
  float m = sum[ch]*(1.f/50176.f);
  float v = sq[ch]*(1.f/50176.f) - m*m;
  float s = ldin(g,ch,f) * rsqrtf(v+1e-5f);
  sc[ch]=s; sh[ch]=ldin(be,ch,f) - m*s;
}

// ---- xatt1 = relu(bn1(y1)), stored transposed [b][p][ch] for involution ----
__global__ void k_bn1(const bf16* y1, const float* sc, const float* sh, bf16* xatt1){
  __shared__ unsigned short tl[64][258];
  int tid=threadIdx.x; int p0=blockIdx.x*64; int b=blockIdx.y;
  for(int k=0;k<64;k++){
    int idx=k*256+tid; int ch=idx>>6, pp=idx&63;
    float v=b2f(y1[((size_t)b*256+ch)*PP + p0+pp]);
    v = v*sc[ch]+sh[ch]; v = v>0?v:0;
    bf16 h=f2b(v); tl[pp][ch]=*(unsigned short*)&h;
  }
  __syncthreads();
  for(int k=0;k<64;k++){
    unsigned short u=tl[k][tid];
    xatt1[((size_t)b*PP + p0+k)*256 + tid] = *(bf16*)&u;
  }
}

// ---- involution: out[C,p] = sum_{i,j} kern[i,j,p] * xatt1[C, shifted] ----
__global__ __launch_bounds__(64) void k_inv(const bf16* xatt1, const float* kern, bf16* inv){
  __shared__ __align__(16) unsigned short xt[196*72];   // rows padded 64->72 (bank spread)
  int tid=threadIdx.x;
  int bx=blockIdx.x, by=blockIdx.y, bz=blockIdx.z;
  int t=bz&7, b=bz>>3;
  int y0=(bx/7)*8, x0=(bx%7)*8, c0=by*64;
  int ty=tid>>3, tx=tid&7;
  for(int e=tid;e<1568;e+=64){
    int row=e>>3, seg=e&7;
    int yy=row/14, xx=row%14;
    int gy=y0+yy-3, gx=x0+xx-3;
    uint4 v={0,0,0,0};
    if(gy>=0&&gy<56&&gx>=0&&gx<56)
      v = *(const uint4*)&xatt1[((size_t)b*PP + t*3136 + gy*56+gx)*256 + c0 + seg*8];
    *(uint4*)&xt[row*72+seg*8]=v;
  }
  float kr[49];
  size_t px=(size_t)t*3136 + (y0+ty)*56 + x0+tx;
  #pragma unroll
  for(int kk=0;kk<49;kk++) kr[kk]=kern[((size_t)b*49+kk)*PP+px];
  __syncthreads();
  for(int sub=0;sub<8;sub++){
    float acc[8];
    #pragma unroll
    for(int e=0;e<8;e++) acc[e]=0;
    for(int i=0;i<7;i++){
      #pragma unroll
      for(int j=0;j<7;j++){
        uint4 u = *(const uint4*)&xt[((ty+i)*14+tx+j)*72 + sub*8];
        float kv = kr[i*7+j];
        acc[0]+=kv*blo(u.x); acc[1]+=kv*bhi(u.x);
        acc[2]+=kv*blo(u.y); acc[3]+=kv*bhi(u.y);
        acc[4]+=kv*blo(u.z); acc[5]+=kv*bhi(u.z);
        acc[6]+=kv*blo(u.w); acc[7]+=kv*bhi(u.w);
      }
    }
    #pragma unroll
    for(int e=0;e<8;e++)
      inv[((size_t)b*256+c0+sub*8+e)*PP+px]=f2b(acc[e]);
  }
}

// ---- out = W_p2 * (bn2(inv) + x_Att) + b_p2  (f32 output) ----
__global__ void k_final(const bf16* inv, const bf16* xatt, const float* wf,
                        const float* sc2, const float* sh2, float* out){
  int p=blockIdx.x*256+threadIdx.x; int o0=blockIdx.y*16; int b=blockIdx.z;
  float acc[16];
  #pragma unroll
  for(int o=0;o<16;o++) acc[o]=wf[oBP2+o0+o];
  const bf16* ip = inv + (size_t)b*256*PP + p;
  const bf16* xp = xatt + (size_t)b*256*PP + p;
  for(int ci=0;ci<256;ci++){
    float v = b2f(ip[(size_t)ci*PP])*sc2[ci]+sh2[ci] + b2f(xp[(size_t)ci*PP]);
    const float* w = wf + oWP2 + ci*64 + o0;
    #pragma unroll
    for(int o=0;o<16;o++) acc[o]+=w[o]*v;
  }
  float* op = out + ((size_t)b*64+o0)*PP + p;
  #pragma unroll
  for(int o=0;o<16;o++) op[(size_t)o*PP]=acc[o];
}

extern "C" void kernel_launch(void* const* d_in, const int* in_sizes, int n_in,
                              void* d_out, int out_size, void* d_ws, size_t ws_size,
                              hipStream_t stream){
  const void* xct_r =d_in[0];
  const void* xwsi_r=d_in[1];
  const void* Wct =d_in[2];
  const void* bct =d_in[3];
  const void* Wwsi=d_in[4];
  const void* bwsi=d_in[5];
  const void* Watt=d_in[6];
  const void* Winv=d_in[7];
  const void* binv=d_in[8];
  const void* Wrr =d_in[9];
  const void* g1  =d_in[10];
  const void* be1 =d_in[11];
  const void* g2  =d_in[12];
  const void* be2 =d_in[13];
  const void* Wp1 =d_in[14];
  const void* Wp2 =d_in[16];
  const void* bp2 =d_in[17];
  float* ws=(float*)d_ws;
  float* x1=ws+X1o; float* pool=ws+POOLo; float* xw1=ws+XW1o;
  float* Wx=ws+WXo; float* WxT=ws+WXTo; float* Wix=ws+WIXo;
  float* att=ws+ATTo; float* kern=ws+KERNo; float* xw3=ws+XW3o;
  float* stat=ws+STATo; float* wf=ws+WFo;
  float* Wattf=ws+WATTFo; float* Winvf=ws+WINVFo;
  int* flag=(int*)(ws+FLAGo);
  bf16* bfb=(bf16*)(ws+BF16o);
  bf16* xctb=bfb+bXCT; bf16* xwsib=bfb+bXWSI;
  bf16* xatt=bfb+bXATT; bf16* y1=bfb+bY1; bf16* invb=bfb+bINV; bf16* xatt1=bfb+bXATT1;
  float* sum1=stat; float* sq1=stat+256; float* sum2=stat+512; float* sq2=stat+768;
  float* sc1=stat+1024; float* sh1=stat+1280; float* sc2=stat+1536; float* sh2=stat+1792;

  hipMemsetAsync(stat,0,4096,stream);
  k_detect<<<1,64,0,stream>>>((const unsigned short*)xct_r,flag);
  k_c2b   <<<12544,256,0,stream>>>(xct_r,xctb,3211264,flag);
  k_c2b   <<<18816,256,0,stream>>>(xwsi_r,xwsib,4816896,flag);
  k_c2f   <<<3733,256,0,stream>>>(Watt,Wattf,955500,flag);
  k_c2f   <<<113,256,0,stream>>>(Winv,Winvf,28812,flag);
  k_cvt   <<<461,256,0,stream>>>(Wct,bct,Wwsi,bwsi,Wrr,binv,Wp1,Wp2,bp2,wf,flag);
  k_pool  <<<294,256,0,stream>>>(xwsib,pool);
  k_xw1   <<<294,256,0,stream>>>(pool,wf,xw1);
  k_Wx    <<<813,256,0,stream>>>(Wattf,xw1,Wx);
  k_WxT   <<<1000,256,0,stream>>>(Wx,WxT);
  k_Winvx <<<25,256,0,stream>>>(Winvf,xw1,Wix);
  k_x1    <<<dim3(98,4,2),256,0,stream>>>(xctb,wf,x1);
  k_att   <<<dim3(16,8,2),256,0,stream>>>(x1,WxT,att);
  k_kern  <<<dim3(98,2),256,0,stream>>>(x1,Wix,wf,kern);
  k_rr    <<<dim3(49,12,2),64,0,stream>>>(xwsib,wf,xw3);
  k_xatt  <<<50176,256,0,stream>>>(xctb,xw3,att,xatt);
  k_p1    <<<dim3(98,16,2),256,0,stream>>>(xatt,wf,y1);
  k_stats <<<dim3(8,256,2),256,0,stream>>>(y1,sum1,sq1);
  k_finstat<<<1,256,0,stream>>>(sum1,sq1,g1,be1,flag,sc1,sh1);
  k_bn1   <<<dim3(392,2),256,0,stream>>>(y1,sc1,sh1,xatt1);
  k_inv   <<<dim3(49,4,16),64,0,stream>>>(xatt1,kern,invb);
  k_stats <<<dim3(8,256,2),256,0,stream>>>(invb,sum2,sq2);
  k_finstat<<<1,256,0,stream>>>(sum2,sq2,g2,be2,flag,sc2,sh2);
  k_final <<<dim3(98,4,2),256,0,stream>>>(invb,xatt,wf,sc2,sh2,(float*)d_out);
}

// Round 4
// 1062.561 us; speedup vs baseline: 1.7086x; 1.7086x over previous
//
#include <hip/hip_runtime.h>
#include <hip/hip_bf16.h>
#include <math.h>

typedef __hip_bfloat16 bf16;
#define DEV static __device__ __forceinline__
DEV float b2f(bf16 x){ return __bfloat162float(x); }
DEV bf16  f2b(float x){ return __float2bfloat16(x); }
DEV float blo(unsigned int w){ return __uint_as_float(w<<16); }
DEV float bhi(unsigned int w){ return __uint_as_float(w&0xffff0000u); }
DEV float ldin(const void* p, long i, int f){
  return f ? ((const float*)p)[i] : b2f(((const bf16*)p)[i]);
}

// problem dims
#define PP 25088            // t*h*w = 8*56*56

// ws layout (float units)
#define X1o    0L           // 2*64*25088
#define POOLo  3211264L     // 2*588*64   [b][m][c]
#define XW1o   3286528L     // 2*588*64   [b][m][c]
#define WXo    3361792L     // 2*13*125*64
#define WXTo   3569792L     // 2*125*64*16 (o padded 13->16, o inner)
#define WIXo   3825792L     // 2*64*49    [b][c][kk]
#define ATTo   3832064L     // 2*13*25088 (post-sigmoid)
#define KERNo  4484352L     // 2*49*25088
#define XW3o   6942976L     // 2*16*12*3136
#define STATo  8147200L     // sums(1024) + scale/shift(1024)
#define FLAGo  8149248L     // dtype flag (int), 16 floats reserved
#define WFo    8149264L     // converted f32 weights (118016)
#define WATTFo 8267280L     // W_att as f32 (955500, pad 955504)
#define WINVFo 9222784L     // W_inv as f32 (28812, pad 28816)
#define BF16o  9251600L     // bf16 region starts here (float idx)
#define PARTo  KERNo        // k_att partials (2,609,152 f) alias KERN+XW3 head;
                            // consumed by k_sig BEFORE k_kern/k_rr write those regions
// wf sub-offsets
#define oWCT   0            // [ci][co] 64x64
#define oBCT   4096
#define oWWSI  4160         // [co][ci] (untransposed)
#define oBWSI  8256
#define oWRR   8320         // [(ci*27+tap)*16+co]
#define oBINV  35968
#define oWP1   36032        // [ci][co] 256x256
#define oWP2   101568       // [ci][co] 256x64
#define oBP2   117952
// bf16 sub-offsets (bf16 element units)
#define bXCT   0L           // 3211264
#define bXWSI  3211264L     // 4816896
#define bXATT  8028160L     // 12845056
#define bY1    20873216L    // 12845056
#define bINV   20873216L    // alias: y1 dead after k_bn1
#define bXATT1 33718272L    // 12845056

// ---- input dtype probe: even uint16s of an f32 buffer are mantissa garbage ----
__global__ void k_detect(const unsigned short* raw, int* flag){
  int t = threadIdx.x;                       // 64 lanes
  unsigned short u = raw[2*t];               // low half of f32 word t (if f32)
  int e = (u>>7)&0xFF;
  int hit = (e >= 137);                      // |bf16| >= 1024 or inf/nan: impossible for N(0,1) bf16
  unsigned long long m = __ballot(hit);
  if(t==0) flag[0] = (__popcll(m) >= 8) ? 1 : 0;   // 1 = inputs are f32
}

// ---- canonicalize inputs ----
__global__ void k_c2b(const void* src, bf16* dst, int n, const int* flag){
  int i = blockIdx.x*256+threadIdx.x; if(i>=n) return;
  int f = flag[0];
  dst[i] = f ? f2b(((const float*)src)[i]) : ((const bf16*)src)[i];
}
__global__ void k_c2f(const void* src, float* dst, int n, const int* flag){
  int i = blockIdx.x*256+threadIdx.x; if(i>=n) return;
  dst[i] = ldin(src, i, flag[0]);
}

// ---- weight convert (+transpose to put out-channel innermost) ----
__global__ void k_cvt(const void* Wct,const void* bct,const void* Wwsi,const void* bwsi,
                      const void* Wrr,const void* binv,const void* Wp1,const void* Wp2,
                      const void* bp2,float* wf,const int* flag){
  int i = blockIdx.x*256 + threadIdx.x;
  int f = flag[0];
  if (i < 4096){ int co=i>>6, ci=i&63; wf[oWCT + ci*64+co] = ldin(Wct,i,f); }
  else if (i < 4160){ wf[i] = ldin(bct,i-4096,f); }
  else if (i < 8256){ wf[i] = ldin(Wwsi,i-4160,f); }
  else if (i < 8320){ wf[i] = ldin(bwsi,i-8256,f); }
  else if (i < 35968){ int l=i-8320; int co=l/1728, r=l%1728, ci=r/27, tp=r%27;
                       wf[oWRR + (ci*27+tp)*16+co] = ldin(Wrr,l,f); }
  else if (i < 36017){ wf[oBINV + (i-35968)] = ldin(binv,i-35968,f); }
  else if (i < 36032){ }
  else if (i < 101568){ int l=i-36032; int co=l>>8, ci=l&255; wf[oWP1 + ci*256+co] = ldin(Wp1,l,f); }
  else if (i < 117952){ int l=i-101568; int o=l>>8, ci=l&255; wf[oWP2 + ci*64+o] = ldin(Wp2,l,f); }
  else if (i < 118016){ int l=i-117952; if(l<64) wf[oBP2 + l] = ldin(bp2,l,f); }
}

// ---- adaptive pool of raw x_WSI (pool commutes with 1x1 conv) ----
__global__ void k_pool(const bf16* xwsi, float* pool){
  int i = blockIdx.x*256+threadIdx.x;            // 75264 = 2*588*64
  int c = i&63; int m=(i>>6)%588; int b=i/37632;
  int d=m/49, r=m%49, ii=r/7, jj=r%7;
  const bf16* src = xwsi + ((size_t)(b*64+c)*12 + d)*3136 + (ii*8)*56 + jj*8;
  float s=0;
  for(int u=0;u<8;u++) for(int v=0;v<8;v++) s += b2f(src[u*56+v]);
  pool[i] = s*(1.f/64.f);
}

// ---- xw1 = W_wsi * pooled + b ; layout [b][m][c] ----
__global__ void k_xw1(const float* pool, const float* wf, float* xw1){
  int i = blockIdx.x*256+threadIdx.x;
  int c = i&63; int m=(i>>6)%588; int b=i/37632;
  const float* p = pool + (b*588+m)*64;
  const float* w = wf + oWWSI + c*64;
  float s = wf[oBWSI + c];
  for(int ci=0;ci<64;ci++) s += w[ci]*p[ci];
  xw1[i]=s;
}

// ---- Wx[b,o,tap,c] = sum_m W_att[o,m,tap] * xw1[b,c,m] ----
__global__ void k_Wx(const float* Wattf, const float* xw1, float* Wx){
  int i = blockIdx.x*256+threadIdx.x; if(i>=208000) return;
  int c=i&63; int r=i>>6; int tap=r%125; int o=(r/125)%13; int b=r/1625;
  const float* wa = Wattf + (size_t)o*588*125 + tap;
  const float* xp = xw1 + b*588*64 + c;
  float s=0;
  for(int m=0;m<588;m++) s += wa[(size_t)m*125] * xp[m*64];
  Wx[i]=s;
}
__global__ void k_WxT(const float* Wx, float* WxT){
  int i = blockIdx.x*256+threadIdx.x; if(i>=256000) return;
  int o=i&15; int c=(i>>4)&63; int tap=(i>>10)%125; int b=i/128000;
  WxT[i] = (o<13) ? Wx[((b*13+o)*125+tap)*64+c] : 0.f;
}

// ---- Winvx[b][c][kk] = sum_m W_inv[kk,m] * xw1[b,c,m] ----
__global__ void k_Winvx(const float* Winvf, const float* xw1, float* Wix){
  int i = blockIdx.x*256+threadIdx.x; if(i>=6272) return;
  int kk=i%49; int c=(i/49)&63; int b=i/3136;
  const float* xp = xw1 + b*588*64 + c;
  float s=0;
  for(int m=0;m<588;m++) s += Winvf[kk*588+m] * xp[m*64];
  Wix[i]=s;
}

// ---- x1 = W_ct * x_CT + b (f32) ----
__global__ void k_x1(const bf16* xct, const float* wf, float* x1){
  int p = blockIdx.x*256+threadIdx.x;
  int co0 = blockIdx.y*16; int b = blockIdx.z;
  float acc[16];
  #pragma unroll
  for(int o=0;o<16;o++) acc[o]=wf[oBCT+co0+o];
  const bf16* xp = xct + (size_t)b*64*PP + p;
  for(int ci=0;ci<64;ci++){
    float xv = b2f(xp[(size_t)ci*PP]);
    const float* w = wf + oWCT + ci*64 + co0;
    #pragma unroll
    for(int o=0;o<16;o++) acc[o] += w[o]*xv;
  }
  float* out = x1 + ((size_t)b*64+co0)*PP + p;
  #pragma unroll
  for(int o=0;o<16;o++) out[(size_t)o*PP]=acc[o];
}

// ---- Att partial: each block reduces a 16-channel slice; 4x blocks for occupancy ----
// part[cg][b][o][p] ; bank-conflict-free LDS (row stride 24 -> 2-way only)
__global__ __launch_bounds__(256) void k_att(const float* x1, const float* WxT, float* part){
  __shared__ float xt[16][20][24];
  int tid=threadIdx.x;
  int bx=blockIdx.x, t=blockIdx.y;
  int b=blockIdx.z>>2, cg=blockIdx.z&3;
  int y0=(bx>>2)*16, x0=(bx&3)*16;
  int ty=tid>>4, tx=tid&15;
  int c0=cg*16;
  float acc[13];
  #pragma unroll
  for(int o=0;o<13;o++) acc[o]=0;
  for(int dt=0;dt<5;dt++){
    int ti=t+dt-2; if(ti<0||ti>=8) continue;
    __syncthreads();
    for(int e=tid;e<6400;e+=256){
      int c=e/400, rm=e%400, yy=rm/20, xx=rm%20;
      int gy=y0+yy-2, gx=x0+xx-2;
      float v=0;
      if(gy>=0&&gy<56&&gx>=0&&gx<56)
        v = x1[((size_t)(b*64+c0+c)*8+ti)*3136 + gy*56+gx];
      xt[c][yy][xx]=v;
    }
    __syncthreads();
    const float* wb = WxT + ((size_t)(b*125 + dt*25)*64 + c0)*16;
    for(int c=0;c<16;c++){
      for(int dy=0;dy<5;dy++){
        #pragma unroll
        for(int dx=0;dx<5;dx++){
          float xv = xt[c][ty+dy][tx+dx];
          const float* wp = wb + ((dy*5+dx)*64 + c)*16;
          #pragma unroll
          for(int o=0;o<13;o++) acc[o] += wp[o]*xv;
        }
      }
    }
  }
  int gy=y0+ty, gx=x0+tx;
  if(gy<56&&gx<56){
    size_t p=(size_t)t*3136+gy*56+gx;
    #pragma unroll
    for(int o=0;o<13;o++)
      part[(((size_t)cg*2+b)*13+o)*PP+p] = acc[o];
  }
}

// ---- att = sigmoid(sum_cg part) ----
__global__ void k_sig(const float* part, float* att){
  int i=blockIdx.x*256+threadIdx.x; if(i>=652288) return;
  int p=i%PP; int r=i/PP; int o=r%13; int b=r/13;
  float s=0;
  #pragma unroll
  for(int cg=0;cg<4;cg++) s += part[(((size_t)cg*2+b)*13+o)*PP+p];
  att[i] = 1.f/(1.f+__expf(-s));
}

// ---- kern49 = Winvx * x1 + b_inv ----
__global__ void k_kern(const float* x1, const float* Wix, const float* wf, float* kern){
  int p = blockIdx.x*256+threadIdx.x; int b=blockIdx.y;
  float acc[49];
  #pragma unroll
  for(int kk=0;kk<49;kk++) acc[kk]=wf[oBINV+kk];
  const float* xp = x1 + (size_t)b*64*PP + p;
  for(int c=0;c<64;c++){
    float xv = xp[(size_t)c*PP];
    const float* w = Wix + (b*64+c)*49;
    #pragma unroll
    for(int kk=0;kk<49;kk++) acc[kk]+=w[kk]*xv;
  }
  float* out = kern + (size_t)b*49*PP + p;
  #pragma unroll
  for(int kk=0;kk<49;kk++) out[(size_t)kk*PP]=acc[kk];
}

// ---- xw3 = conv3x3x3(x_WSI, W_rr, pad=1) ----
__global__ __launch_bounds__(64) void k_rr(const bf16* xwsi, const float* wf, float* xw3){
  __shared__ float xt[16][10][10];
  int tid=threadIdx.x; int bx=blockIdx.x, d=blockIdx.y, b=blockIdx.z;
  int y0=(bx/7)*8, x0=(bx%7)*8;
  int ty=tid>>3, tx=tid&7;
  float acc[16];
  #pragma unroll
  for(int o=0;o<16;o++) acc[o]=0;
  for(int dz=0;dz<3;dz++){
    int di=d+dz-1; if(di<0||di>=12) continue;
    for(int c0=0;c0<64;c0+=16){
      __syncthreads();
      for(int e=tid;e<1600;e+=64){
        int c=e/100, rm=e%100, yy=rm/10, xx=rm%10;
        int gy=y0+yy-1, gx=x0+xx-1;
        float v=0;
        if(gy>=0&&gy<56&&gx>=0&&gx<56)
          v=b2f(xwsi[((size_t)(b*64+c0+c)*12+di)*3136+gy*56+gx]);
        xt[c][yy][xx]=v;
      }
      __syncthreads();
      for(int c=0;c<16;c++){
        #pragma unroll
        for(int dy=0;dy<3;dy++){
          #pragma unroll
          for(int dx=0;dx<3;dx++){
            float xv=xt[c][ty+dy][tx+dx];
            const float* w = wf + oWRR + ((c0+c)*27 + dz*9+dy*3+dx)*16;
            #pragma unroll
            for(int o=0;o<16;o++) acc[o]+=w[o]*xv;
          }
        }
      }
    }
  }
  float* out = xw3 + ((size_t)b*16*12 + d)*3136 + (y0+ty)*56+x0+tx;
  #pragma unroll
  for(int o=0;o<16;o++) out[(size_t)o*12*3136]=acc[o];
}

// ---- x_Att = x_FS * (1 + Att_FS)  (bf16) ----
__global__ void k_xatt(const bf16* xct, const float* xw3, const float* att, bf16* xatt){
  size_t i=(size_t)blockIdx.x*256+threadIdx.x;   // 12,845,056
  int p=(int)(i%PP); int ch=(int)((i/PP)&255); int b=(int)(i/((size_t)PP*256));
  int s=p%3136;
  float v;
  if(ch<64){
    v = b2f(xct[((size_t)b*64+ch)*PP+p]) * (1.f+att[(size_t)b*13*PP+p]);
  } else {
    int q=ch-64;
    v = xw3[((size_t)(b*16+q/12)*12 + q%12)*3136 + s] * (1.f+att[((size_t)b*13+1+q/16)*PP+p]);
  }
  xatt[i]=f2b(v);
}

// ---- y1 = W_p1 * x_Att  (b_p1 cancels in batchnorm) ----
__global__ void k_p1(const bf16* xatt, const float* wf, bf16* y1){
  int p=blockIdx.x*256+threadIdx.x;
  int co0=blockIdx.y*16; int b=blockIdx.z;
  float acc[16];
  #pragma unroll
  for(int o=0;o<16;o++) acc[o]=0;
  const bf16* xp = xatt + (size_t)b*256*PP + p;
  for(int ci=0;ci<256;ci++){
    float xv=b2f(xp[(size_t)ci*PP]);
    const float* w = wf + oWP1 + ci*256 + co0;
    #pragma unroll
    for(int o=0;o<16;o++) acc[o]+=w[o]*xv;
  }
  bf16* out = y1 + ((size_t)b*256+co0)*PP + p;
  #pragma unroll
  for(int o=0;o<16;o++) out[(size_t)o*PP]=f2b(acc[o]);
}

// ---- per-channel sum / sumsq ----
__global__ void k_stats(const bf16* src, float* sum, float* sq){
  __shared__ float rs[256], rq[256];
  int tid=threadIdx.x;
  int chunk=blockIdx.x, ch=blockIdx.y, b=blockIdx.z;
  const bf16* p = src + ((size_t)b*256+ch)*PP + chunk*3136;
  float s=0,q=0;
  for(int i=tid;i<3136;i+=256){ float v=b2f(p[i]); s+=v; q+=v*v; }
  rs[tid]=s; rq[tid]=q; __syncthreads();
  for(int st=128;st>0;st>>=1){ if(tid<st){rs[tid]+=rs[tid+st]; rq[tid]+=rq[tid+st];} __syncthreads(); }
  if(tid==0){ atomicAdd(&sum[ch],rs[0]); atomicAdd(&sq[ch],rq[0]); }
}
__global__ void k_finstat(const float* sum, const float* sq, const void* g, const void* be,
                          const int* flag, float* sc, float* sh){
  int ch=threadIdx.x;
  int f=flag[0];
  float m = sum[ch]*(1.f/50176.f);
  float v = sq[ch]*(1.f/50176.f) - m*m;
  float s = ldin(g,ch,f) * rsqrtf(v+1e-5f);
  sc[ch]=s; sh[ch]=ldin(be,ch,f) - m*s;
}

// ---- xatt1 = relu(bn1(y1)), stored transposed [b][p][ch] for involution ----
__global__ void k_bn1(const bf16* y1, const float* sc, const float* sh, bf16* xatt1){
  __shared__ unsigned short tl[64][258];
  int tid=threadIdx.x; int p0=blockIdx.x*64; int b=blockIdx.y;
  for(int k=0;k<64;k++){
    int idx=k*256+tid; int ch=idx>>6, pp=idx&63;
    float v=b2f(y1[((size_t)b*256+ch)*PP + p0+pp]);
    v = v*sc[ch]+sh[ch]; v = v>0?v:0;
    bf16 h=f2b(v); tl[pp][ch]=*(unsigned short*)&h;
  }
  __syncthreads();
  for(int k=0;k<64;k++){
    unsigned short u=tl[k][tid];
    xatt1[((size_t)b*PP + p0+k)*256 + tid] = *(bf16*)&u;
  }
}

// ---- involution: out[C,p] = sum_{i,j} kern[i,j,p] * xatt1[C, shifted] ----
__global__ __launch_bounds__(64) void k_inv(const bf16* xatt1, const float* kern, bf16* inv){
  __shared__ __align__(16) unsigned short xt[196*72];   // rows padded 64->72 (bank spread)
  int tid=threadIdx.x;
  int bx=blockIdx.x, by=blockIdx.y, bz=blockIdx.z;
  int t=bz&7, b=bz>>3;
  int y0=(bx/7)*8, x0=(bx%7)*8, c0=by*64;
  int ty=tid>>3, tx=tid&7;
  for(int e=tid;e<1568;e+=64){
    int row=e>>3, seg=e&7;
    int yy=row/14, xx=row%14;
    int gy=y0+yy-3, gx=x0+xx-3;
    uint4 v={0,0,0,0};
    if(gy>=0&&gy<56&&gx>=0&&gx<56)
      v = *(const uint4*)&xatt1[((size_t)b*PP + t*3136 + gy*56+gx)*256 + c0 + seg*8];
    *(uint4*)&xt[row*72+seg*8]=v;
  }
  float kr[49];
  size_t px=(size_t)t*3136 + (y0+ty)*56 + x0+tx;
  #pragma unroll
  for(int kk=0;kk<49;kk++) kr[kk]=kern[((size_t)b*49+kk)*PP+px];
  __syncthreads();
  for(int sub=0;sub<8;sub++){
    float acc[8];
    #pragma unroll
    for(int e=0;e<8;e++) acc[e]=0;
    for(int i=0;i<7;i++){
      #pragma unroll
      for(int j=0;j<7;j++){
        uint4 u = *(const uint4*)&xt[((ty+i)*14+tx+j)*72 + sub*8];
        float kv = kr[i*7+j];
        acc[0]+=kv*blo(u.x); acc[1]+=kv*bhi(u.x);
        acc[2]+=kv*blo(u.y); acc[3]+=kv*bhi(u.y);
        acc[4]+=kv*blo(u.z); acc[5]+=kv*bhi(u.z);
        acc[6]+=kv*blo(u.w); acc[7]+=kv*bhi(u.w);
      }
    }
    #pragma unroll
    for(int e=0;e<8;e++)
      inv[((size_t)b*256+c0+sub*8+e)*PP+px]=f2b(acc[e]);
  }
}

// ---- out = W_p2 * (bn2(inv) + x_Att) + b_p2  (f32 output) ----
__global__ void k_final(const bf16* inv, const bf16* xatt, const float* wf,
                        const float* sc2, const float* sh2, float* out){
  int p=blockIdx.x*256+threadIdx.x; int o0=blockIdx.y*16; int b=blockIdx.z;
  float acc[16];
  #pragma unroll
  for(int o=0;o<16;o++) acc[o]=wf[oBP2+o0+o];
  const bf16* ip = inv + (size_t)b*256*PP + p;
  const bf16* xp = xatt + (size_t)b*256*PP + p;
  for(int ci=0;ci<256;ci++){
    float v = b2f(ip[(size_t)ci*PP])*sc2[ci]+sh2[ci] + b2f(xp[(size_t)ci*PP]);
    const float* w = wf + oWP2 + ci*64 + o0;
    #pragma unroll
    for(int o=0;o<16;o++) acc[o]+=w[o]*v;
  }
  float* op = out + ((size_t)b*64+o0)*PP + p;
  #pragma unroll
  for(int o=0;o<16;o++) op[(size_t)o*PP]=acc[o];
}

extern "C" void kernel_launch(void* const* d_in, const int* in_sizes, int n_in,
                              void* d_out, int out_size, void* d_ws, size_t ws_size,
                              hipStream_t stream){
  const void* xct_r =d_in[0];
  const void* xwsi_r=d_in[1];
  const void* Wct =d_in[2];
  const void* bct =d_in[3];
  const void* Wwsi=d_in[4];
  const void* bwsi=d_in[5];
  const void* Watt=d_in[6];
  const void* Winv=d_in[7];
  const void* binv=d_in[8];
  const void* Wrr =d_in[9];
  const void* g1  =d_in[10];
  const void* be1 =d_in[11];
  const void* g2  =d_in[12];
  const void* be2 =d_in[13];
  const void* Wp1 =d_in[14];
  const void* Wp2 =d_in[16];
  const void* bp2 =d_in[17];
  float* ws=(float*)d_ws;
  float* x1=ws+X1o; float* pool=ws+POOLo; float* xw1=ws+XW1o;
  float* Wx=ws+WXo; float* WxT=ws+WXTo; float* Wix=ws+WIXo;
  float* att=ws+ATTo; float* kern=ws+KERNo; float* xw3=ws+XW3o;
  float* part=ws+PARTo;
  float* stat=ws+STATo; float* wf=ws+WFo;
  float* Wattf=ws+WATTFo; float* Winvf=ws+WINVFo;
  int* flag=(int*)(ws+FLAGo);
  bf16* bfb=(bf16*)(ws+BF16o);
  bf16* xctb=bfb+bXCT; bf16* xwsib=bfb+bXWSI;
  bf16* xatt=bfb+bXATT; bf16* y1=bfb+bY1; bf16* invb=bfb+bINV; bf16* xatt1=bfb+bXATT1;
  float* sum1=stat; float* sq1=stat+256; float* sum2=stat+512; float* sq2=stat+768;
  float* sc1=stat+1024; float* sh1=stat+1280; float* sc2=stat+1536; float* sh2=stat+1792;

  hipMemsetAsync(stat,0,4096,stream);
  k_detect<<<1,64,0,stream>>>((const unsigned short*)xct_r,flag);
  k_c2b   <<<12544,256,0,stream>>>(xct_r,xctb,3211264,flag);
  k_c2b   <<<18816,256,0,stream>>>(xwsi_r,xwsib,4816896,flag);
  k_c2f   <<<3733,256,0,stream>>>(Watt,Wattf,955500,flag);
  k_c2f   <<<113,256,0,stream>>>(Winv,Winvf,28812,flag);
  k_cvt   <<<461,256,0,stream>>>(Wct,bct,Wwsi,bwsi,Wrr,binv,Wp1,Wp2,bp2,wf,flag);
  k_pool  <<<294,256,0,stream>>>(xwsib,pool);
  k_xw1   <<<294,256,0,stream>>>(pool,wf,xw1);
  k_Wx    <<<813,256,0,stream>>>(Wattf,xw1,Wx);
  k_WxT   <<<1000,256,0,stream>>>(Wx,WxT);
  k_Winvx <<<25,256,0,stream>>>(Winvf,xw1,Wix);
  k_x1    <<<dim3(98,4,2),256,0,stream>>>(xctb,wf,x1);
  k_att   <<<dim3(16,8,8),256,0,stream>>>(x1,WxT,part);     // 1024 blocks, 4/CU
  k_sig   <<<2548,256,0,stream>>>(part,att);                // consumes part before k_kern/k_rr reuse it
  k_kern  <<<dim3(98,2),256,0,stream>>>(x1,Wix,wf,kern);
  k_rr    <<<dim3(49,12,2),64,0,stream>>>(xwsib,wf,xw3);
  k_xatt  <<<50176,256,0,stream>>>(xctb,xw3,att,xatt);
  k_p1    <<<dim3(98,16,2),256,0,stream>>>(xatt,wf,y1);
  k_stats <<<dim3(8,256,2),256,0,stream>>>(y1,sum1,sq1);
  k_finstat<<<1,256,0,stream>>>(sum1,sq1,g1,be1,flag,sc1,sh1);
  k_bn1   <<<dim3(392,2),256,0,stream>>>(y1,sc1,sh1,xatt1);
  k_inv   <<<dim3(49,4,16),64,0,stream>>>(xatt1,kern,invb);
  k_stats <<<dim3(8,256,2),256,0,stream>>>(invb,sum2,sq2);
  k_finstat<<<1,256,0,stream>>>(sum2,sq2,g2,be2,flag,sc2,sh2);
  k_final <<<dim3(98,4,2),256,0,stream>>>(invb,xatt,wf,sc2,sh2,(float*)d_out);
}

// Round 5
// 1020.693 us; speedup vs baseline: 1.7786x; 1.0410x over previous
//
#include <hip/hip_runtime.h>
#include <hip/hip_bf16.h>
#include <math.h>

typedef __hip_bfloat16 bf16;
#define DEV static __device__ __forceinline__
DEV float b2f(bf16 x){ return __bfloat162float(x); }
DEV bf16  f2b(float x){ return __float2bfloat16(x); }
DEV float blo(unsigned int w){ return __uint_as_float(w<<16); }
DEV float bhi(unsigned int w){ return __uint_as_float(w&0xffff0000u); }
DEV float ldin(const void* p, long i, int f){
  return f ? ((const float*)p)[i] : b2f(((const bf16*)p)[i]);
}

// problem dims
#define PP 25088            // t*h*w = 8*56*56

// ws layout (float units)
#define X1o    0L           // 2*64*25088
#define POOLo  3211264L     // 2*588*64   [b][m][c]
#define XW1o   3286528L     // 2*588*64   [b][m][c]
#define WXo    3361792L     // 2*13*125*64
#define WXTo   3569792L     // 2*125*64*16 (o padded 13->16, o inner)
#define WIXo   3825792L     // 2*64*49    [b][c][kk]
#define ATTo   3832064L     // 2*13*25088 (post-sigmoid)
#define KERNo  4484352L     // 2*49*25088
#define XW3o   6942976L     // 2*16*12*3136
#define STATo  8147200L     // sums(1024) + scale/shift(1024)
#define FLAGo  8149248L     // dtype flag (int), 16 floats reserved
#define WFo    8149264L     // converted f32 weights (118016)
#define WATTFo 8267280L     // W_att as f32 (955500, pad 955504)
#define WINVFo 9222784L     // W_inv as f32 (28812, pad 28816)
#define BF16o  9251600L     // bf16 region starts here (float idx)
#define PARTo  KERNo        // k_att partials (2,609,152 f) alias KERN+XW3 head;
                            // consumed by k_sig BEFORE k_kern/k_rr write those regions
// wf sub-offsets
#define oWCT   0            // [ci][co] 64x64
#define oBCT   4096
#define oWWSI  4160         // [co][ci] (untransposed)
#define oBWSI  8256
#define oWRR   8320         // [(ci*27+tap)*16+co]
#define oBINV  35968
#define oWP1   36032        // [ci][co] 256x256
#define oWP2   101568       // [ci][co] 256x64
#define oBP2   117952
// bf16 sub-offsets (bf16 element units)
#define bXCT   0L           // 3211264
#define bXWSI  3211264L     // 4816896
#define bXATT  8028160L     // 12845056
#define bY1    20873216L    // 12845056
#define bINV   20873216L    // alias: y1 dead after k_bn1
#define bXATT1 33718272L    // 12845056

// ---- input dtype probe: even uint16s of an f32 buffer are mantissa garbage ----
__global__ void k_detect(const unsigned short* raw, int* flag){
  int t = threadIdx.x;                       // 64 lanes
  unsigned short u = raw[2*t];               // low half of f32 word t (if f32)
  int e = (u>>7)&0xFF;
  int hit = (e >= 137);                      // |bf16| >= 1024 or inf/nan: impossible for N(0,1) bf16
  unsigned long long m = __ballot(hit);
  if(t==0) flag[0] = (__popcll(m) >= 8) ? 1 : 0;   // 1 = inputs are f32
}

// ---- canonicalize inputs ----
__global__ void k_c2b(const void* src, bf16* dst, int n, const int* flag){
  int i = blockIdx.x*256+threadIdx.x; if(i>=n) return;
  int f = flag[0];
  dst[i] = f ? f2b(((const float*)src)[i]) : ((const bf16*)src)[i];
}
__global__ void k_c2f(const void* src, float* dst, int n, const int* flag){
  int i = blockIdx.x*256+threadIdx.x; if(i>=n) return;
  dst[i] = ldin(src, i, flag[0]);
}

// ---- weight convert (+transpose to put out-channel innermost) ----
__global__ void k_cvt(const void* Wct,const void* bct,const void* Wwsi,const void* bwsi,
                      const void* Wrr,const void* binv,const void* Wp1,const void* Wp2,
                      const void* bp2,float* wf,const int* flag){
  int i = blockIdx.x*256 + threadIdx.x;
  int f = flag[0];
  if (i < 4096){ int co=i>>6, ci=i&63; wf[oWCT + ci*64+co] = ldin(Wct,i,f); }
  else if (i < 4160){ wf[i] = ldin(bct,i-4096,f); }
  else if (i < 8256){ wf[i] = ldin(Wwsi,i-4160,f); }
  else if (i < 8320){ wf[i] = ldin(bwsi,i-8256,f); }
  else if (i < 35968){ int l=i-8320; int co=l/1728, r=l%1728, ci=r/27, tp=r%27;
                       wf[oWRR + (ci*27+tp)*16+co] = ldin(Wrr,l,f); }
  else if (i < 36017){ wf[oBINV + (i-35968)] = ldin(binv,i-35968,f); }
  else if (i < 36032){ }
  else if (i < 101568){ int l=i-36032; int co=l>>8, ci=l&255; wf[oWP1 + ci*256+co] = ldin(Wp1,l,f); }
  else if (i < 117952){ int l=i-101568; int o=l>>8, ci=l&255; wf[oWP2 + ci*64+o] = ldin(Wp2,l,f); }
  else if (i < 118016){ int l=i-117952; if(l<64) wf[oBP2 + l] = ldin(bp2,l,f); }
}

// ---- adaptive pool of raw x_WSI (pool commutes with 1x1 conv) ----
__global__ void k_pool(const bf16* xwsi, float* pool){
  int i = blockIdx.x*256+threadIdx.x;            // 75264 = 2*588*64
  int c = i&63; int m=(i>>6)%588; int b=i/37632;
  int d=m/49, r=m%49, ii=r/7, jj=r%7;
  const bf16* src = xwsi + ((size_t)(b*64+c)*12 + d)*3136 + (ii*8)*56 + jj*8;
  float s=0;
  for(int u=0;u<8;u++) for(int v=0;v<8;v++) s += b2f(src[u*56+v]);
  pool[i] = s*(1.f/64.f);
}

// ---- xw1 = W_wsi * pooled + b ; layout [b][m][c] ----
__global__ void k_xw1(const float* pool, const float* wf, float* xw1){
  int i = blockIdx.x*256+threadIdx.x;
  int c = i&63; int m=(i>>6)%588; int b=i/37632;
  const float* p = pool + (b*588+m)*64;
  const float* w = wf + oWWSI + c*64;
  float s = wf[oBWSI + c];
  for(int ci=0;ci<64;ci++) s += w[ci]*p[ci];
  xw1[i]=s;
}

// ---- Wx[b,o,tap,c] = sum_m W_att[o,m,tap] * xw1[b,c,m] ----
__global__ void k_Wx(const float* Wattf, const float* xw1, float* Wx){
  int i = blockIdx.x*256+threadIdx.x; if(i>=208000) return;
  int c=i&63; int r=i>>6; int tap=r%125; int o=(r/125)%13; int b=r/1625;
  const float* wa = Wattf + (size_t)o*588*125 + tap;
  const float* xp = xw1 + b*588*64 + c;
  float s=0;
  for(int m=0;m<588;m++) s += wa[(size_t)m*125] * xp[m*64];
  Wx[i]=s;
}
__global__ void k_WxT(const float* Wx, float* WxT){
  int i = blockIdx.x*256+threadIdx.x; if(i>=256000) return;
  int o=i&15; int c=(i>>4)&63; int tap=(i>>10)%125; int b=i/128000;
  WxT[i] = (o<13) ? Wx[((b*13+o)*125+tap)*64+c] : 0.f;
}

// ---- Winvx[b][c][kk] = sum_m W_inv[kk,m] * xw1[b,c,m] ----
__global__ void k_Winvx(const float* Winvf, const float* xw1, float* Wix){
  int i = blockIdx.x*256+threadIdx.x; if(i>=6272) return;
  int kk=i%49; int c=(i/49)&63; int b=i/3136;
  const float* xp = xw1 + b*588*64 + c;
  float s=0;
  for(int m=0;m<588;m++) s += Winvf[kk*588+m] * xp[m*64];
  Wix[i]=s;
}

// ---- x1 = W_ct * x_CT + b (f32) ----
__global__ void k_x1(const bf16* xct, const float* wf, float* x1){
  int p = blockIdx.x*256+threadIdx.x;
  int co0 = blockIdx.y*16; int b = blockIdx.z;
  float acc[16];
  #pragma unroll
  for(int o=0;o<16;o++) acc[o]=wf[oBCT+co0+o];
  const bf16* xp = xct + (size_t)b*64*PP + p;
  for(int ci=0;ci<64;ci++){
    float xv = b2f(xp[(size_t)ci*PP]);
    const float* w = wf + oWCT + ci*64 + co0;
    #pragma unroll
    for(int o=0;o<16;o++) acc[o] += w[o]*xv;
  }
  float* out = x1 + ((size_t)b*64+co0)*PP + p;
  #pragma unroll
  for(int o=0;o<16;o++) out[(size_t)o*PP]=acc[o];
}

// ---- Att partial: each block reduces a 16-channel slice; 4x blocks for occupancy ----
// part[cg][b][o][p] ; bank-conflict-free LDS (row stride 24 -> 2-way only)
__global__ __launch_bounds__(256) void k_att(const float* x1, const float* WxT, float* part){
  __shared__ float xt[16][20][24];
  int tid=threadIdx.x;
  int bx=blockIdx.x, t=blockIdx.y;
  int b=blockIdx.z>>2, cg=blockIdx.z&3;
  int y0=(bx>>2)*16, x0=(bx&3)*16;
  int ty=tid>>4, tx=tid&15;
  int c0=cg*16;
  float acc[13];
  #pragma unroll
  for(int o=0;o<13;o++) acc[o]=0;
  for(int dt=0;dt<5;dt++){
    int ti=t+dt-2; if(ti<0||ti>=8) continue;
    __syncthreads();
    for(int e=tid;e<6400;e+=256){
      int c=e/400, rm=e%400, yy=rm/20, xx=rm%20;
      int gy=y0+yy-2, gx=x0+xx-2;
      float v=0;
      if(gy>=0&&gy<56&&gx>=0&&gx<56)
        v = x1[((size_t)(b*64+c0+c)*8+ti)*3136 + gy*56+gx];
      xt[c][yy][xx]=v;
    }
    __syncthreads();
    const float* wb = WxT + ((size_t)(b*125 + dt*25)*64 + c0)*16;
    for(int c=0;c<16;c++){
      for(int dy=0;dy<5;dy++){
        #pragma unroll
        for(int dx=0;dx<5;dx++){
          float xv = xt[c][ty+dy][tx+dx];
          const float* wp = wb + ((dy*5+dx)*64 + c)*16;
          #pragma unroll
          for(int o=0;o<13;o++) acc[o] += wp[o]*xv;
        }
      }
    }
  }
  int gy=y0+ty, gx=x0+tx;
  if(gy<56&&gx<56){
    size_t p=(size_t)t*3136+gy*56+gx;
    #pragma unroll
    for(int o=0;o<13;o++)
      part[(((size_t)cg*2+b)*13+o)*PP+p] = acc[o];
  }
}

// ---- att = sigmoid(sum_cg part) ----
__global__ void k_sig(const float* part, float* att){
  int i=blockIdx.x*256+threadIdx.x; if(i>=652288) return;
  int p=i%PP; int r=i/PP; int o=r%13; int b=r/13;
  float s=0;
  #pragma unroll
  for(int cg=0;cg<4;cg++) s += part[(((size_t)cg*2+b)*13+o)*PP+p];
  att[i] = 1.f/(1.f+__expf(-s));
}

// ---- kern49 = Winvx * x1 + b_inv ----
__global__ void k_kern(const float* x1, const float* Wix, const float* wf, float* kern){
  int p = blockIdx.x*256+threadIdx.x; int b=blockIdx.y;
  float acc[49];
  #pragma unroll
  for(int kk=0;kk<49;kk++) acc[kk]=wf[oBINV+kk];
  const float* xp = x1 + (size_t)b*64*PP + p;
  for(int c=0;c<64;c++){
    float xv = xp[(size_t)c*PP];
    const float* w = Wix + (b*64+c)*49;
    #pragma unroll
    for(int kk=0;kk<49;kk++) acc[kk]+=w[kk]*xv;
  }
  float* out = kern + (size_t)b*49*PP + p;
  #pragma unroll
  for(int kk=0;kk<49;kk++) out[(size_t)kk*PP]=acc[kk];
}

// ---- xw3 = conv3x3x3(x_WSI, W_rr, pad=1) ----
// 8x14 tile (56 = 7*8 = 4*14, zero tile waste), 128 threads, halo 10x16 in LDS.
__global__ __launch_bounds__(128) void k_rr(const bf16* xwsi, const float* wf, float* xw3){
  __shared__ float xt[16][10][16];    // row stride 16: wave rows alternate bank halves (2-way max)
  int tid=threadIdx.x; int bx=blockIdx.x, d=blockIdx.y, b=blockIdx.z;
  int y0=(bx>>2)*8, x0=(bx&3)*14;     // 7 row-tiles x 4 col-tiles
  int py=tid>>4, tx=tid&15;           // 8 rows x 16 cols (tx<14 active in compute)
  float acc[16];
  #pragma unroll
  for(int o=0;o<16;o++) acc[o]=0;
  for(int dz=0;dz<3;dz++){
    int di=d+dz-1; if(di<0||di>=12) continue;   // block-uniform: barrier-safe
    for(int c0=0;c0<64;c0+=16){
      __syncthreads();
      #pragma unroll
      for(int k=0;k<20;k++){                    // 16ch*10*16 = 2560 / 128
        int e=tid+k*128;
        int c=e/160, rm=e-c*160, yy=rm>>4, xx=rm&15;
        int gy=y0+yy-1, gx=x0+xx-1;
        float v=0;
        if(gy>=0&&gy<56&&gx>=0&&gx<56)
          v=b2f(xwsi[((size_t)(b*64+c0+c)*12+di)*3136+gy*56+gx]);
        xt[c][yy][xx]=v;
      }
      __syncthreads();
      if(tx<14){
        for(int c=0;c<16;c++){
          #pragma unroll
          for(int dy=0;dy<3;dy++){
            #pragma unroll
            for(int dx=0;dx<3;dx++){
              float xv=xt[c][py+dy][tx+dx];
              const float* w = wf + oWRR + ((c0+c)*27 + dz*9+dy*3+dx)*16;
              #pragma unroll
              for(int o=0;o<16;o++) acc[o]+=w[o]*xv;
            }
          }
        }
      }
    }
  }
  if(tx<14){
    float* out = xw3 + ((size_t)b*16*12 + d)*3136 + (y0+py)*56 + x0+tx;
    #pragma unroll
    for(int o=0;o<16;o++) out[(size_t)o*12*3136]=acc[o];
  }
}

// ---- x_Att = x_FS * (1 + Att_FS)  (bf16) ----
__global__ void k_xatt(const bf16* xct, const float* xw3, const float* att, bf16* xatt){
  size_t i=(size_t)blockIdx.x*256+threadIdx.x;   // 12,845,056
  int p=(int)(i%PP); int ch=(int)((i/PP)&255); int b=(int)(i/((size_t)PP*256));
  int s=p%3136;
  float v;
  if(ch<64){
    v = b2f(xct[((size_t)b*64+ch)*PP+p]) * (1.f+att[(size_t)b*13*PP+p]);
  } else {
    int q=ch-64;
    v = xw3[((size_t)(b*16+q/12)*12 + q%12)*3136 + s] * (1.f+att[((size_t)b*13+1+q/16)*PP+p]);
  }
  xatt[i]=f2b(v);
}

// ---- y1 = W_p1 * x_Att  (b_p1 cancels in batchnorm) ----
__global__ void k_p1(const bf16* xatt, const float* wf, bf16* y1){
  int p=blockIdx.x*256+threadIdx.x;
  int co0=blockIdx.y*16; int b=blockIdx.z;
  float acc[16];
  #pragma unroll
  for(int o=0;o<16;o++) acc[o]=0;
  const bf16* xp = xatt + (size_t)b*256*PP + p;
  for(int ci=0;ci<256;ci++){
    float xv=b2f(xp[(size_t)ci*PP]);
    const float* w = wf + oWP1 + ci*256 + co0;
    #pragma unroll
    for(int o=0;o<16;o++) acc[o]+=w[o]*xv;
  }
  bf16* out = y1 + ((size_t)b*256+co0)*PP + p;
  #pragma unroll
  for(int o=0;o<16;o++) out[(size_t)o*PP]=f2b(acc[o]);
}

// ---- per-channel sum / sumsq ----
__global__ void k_stats(const bf16* src, float* sum, float* sq){
  __shared__ float rs[256], rq[256];
  int tid=threadIdx.x;
  int chunk=blockIdx.x, ch=blockIdx.y, b=blockIdx.z;
  const bf16* p = src + ((size_t)b*256+ch)*PP + chunk*3136;
  float s=0,q=0;
  for(int i=tid;i<3136;i+=256){ float v=b2f(p[i]); s+=v; q+=v*v; }
  rs[tid]=s; rq[tid]=q; __syncthreads();
  for(int st=128;st>0;st>>=1){ if(tid<st){rs[tid]+=rs[tid+st]; rq[tid]+=rq[tid+st];} __syncthreads(); }
  if(tid==0){ atomicAdd(&sum[ch],rs[0]); atomicAdd(&sq[ch],rq[0]); }
}
__global__ void k_finstat(const float* sum, const float* sq, const void* g, const void* be,
                          const int* flag, float* sc, float* sh){
  int ch=threadIdx.x;
  int f=flag[0];
  float m = sum[ch]*(1.f/50176.f);
  float v = sq[ch]*(1.f/50176.f) - m*m;
  float s = ldin(g,ch,f) * rsqrtf(v+1e-5f);
  sc[ch]=s; sh[ch]=ldin(be,ch,f) - m*s;
}

// ---- xatt1 = relu(bn1(y1)), stored transposed [b][p][ch] for involution ----
__global__ void k_bn1(const bf16* y1, const float* sc, const float* sh, bf16* xatt1){
  __shared__ unsigned short tl[64][258];
  int tid=threadIdx.x; int p0=blockIdx.x*64; int b=blockIdx.y;
  for(int k=0;k<64;k++){
    int idx=k*256+tid; int ch=idx>>6, pp=idx&63;
    float v=b2f(y1[((size_t)b*256+ch)*PP + p0+pp]);
    v = v*sc[ch]+sh[ch]; v = v>0?v:0;
    bf16 h=f2b(v); tl[pp][ch]=*(unsigned short*)&h;
  }
  __syncthreads();
  for(int k=0;k<64;k++){
    unsigned short u=tl[k][tid];
    xatt1[((size_t)b*PP + p0+k)*256 + tid] = *(bf16*)&u;
  }
}

// ---- involution: out[C,p] = sum_{i,j} kern[i,j,p] * xatt1[C, shifted] ----
__global__ __launch_bounds__(64) void k_inv(const bf16* xatt1, const float* kern, bf16* inv){
  __shared__ __align__(16) unsigned short xt[196*72];   // rows padded 64->72 (bank spread)
  int tid=threadIdx.x;
  int bx=blockIdx.x, by=blockIdx.y, bz=blockIdx.z;
  int t=bz&7, b=bz>>3;
  int y0=(bx/7)*8, x0=(bx%7)*8, c0=by*64;
  int ty=tid>>3, tx=tid&7;
  for(int e=tid;e<1568;e+=64){
    int row=e>>3, seg=e&7;
    int yy=row/14, xx=row%14;
    int gy=y0+yy-3, gx=x0+xx-3;
    uint4 v={0,0,0,0};
    if(gy>=0&&gy<56&&gx>=0&&gx<56)
      v = *(const uint4*)&xatt1[((size_t)b*PP + t*3136 + gy*56+gx)*256 + c0 + seg*8];
    *(uint4*)&xt[row*72+seg*8]=v;
  }
  float kr[49];
  size_t px=(size_t)t*3136 + (y0+ty)*56 + x0+tx;
  #pragma unroll
  for(int kk=0;kk<49;kk++) kr[kk]=kern[((size_t)b*49+kk)*PP+px];
  __syncthreads();
  for(int sub=0;sub<8;sub++){
    float acc[8];
    #pragma unroll
    for(int e=0;e<8;e++) acc[e]=0;
    for(int i=0;i<7;i++){
      #pragma unroll
      for(int j=0;j<7;j++){
        uint4 u = *(const uint4*)&xt[((ty+i)*14+tx+j)*72 + sub*8];
        float kv = kr[i*7+j];
        acc[0]+=kv*blo(u.x); acc[1]+=kv*bhi(u.x);
        acc[2]+=kv*blo(u.y); acc[3]+=kv*bhi(u.y);
        acc[4]+=kv*blo(u.z); acc[5]+=kv*bhi(u.z);
        acc[6]+=kv*blo(u.w); acc[7]+=kv*bhi(u.w);
      }
    }
    #pragma unroll
    for(int e=0;e<8;e++)
      inv[((size_t)b*256+c0+sub*8+e)*PP+px]=f2b(acc[e]);
  }
}

// ---- out = W_p2 * (bn2(inv) + x_Att) + b_p2  (f32 output) ----
__global__ void k_final(const bf16* inv, const bf16* xatt, const float* wf,
                        const float* sc2, const float* sh2, float* out){
  int p=blockIdx.x*256+threadIdx.x; int o0=blockIdx.y*16; int b=blockIdx.z;
  float acc[16];
  #pragma unroll
  for(int o=0;o<16;o++) acc[o]=wf[oBP2+o0+o];
  const bf16* ip = inv + (size_t)b*256*PP + p;
  const bf16* xp = xatt + (size_t)b*256*PP + p;
  for(int ci=0;ci<256;ci++){
    float v = b2f(ip[(size_t)ci*PP])*sc2[ci]+sh2[ci] + b2f(xp[(size_t)ci*PP]);
    const float* w = wf + oWP2 + ci*64 + o0;
    #pragma unroll
    for(int o=0;o<16;o++) acc[o]+=w[o]*v;
  }
  float* op = out + ((size_t)b*64+o0)*PP + p;
  #pragma unroll
  for(int o=0;o<16;o++) op[(size_t)o*PP]=acc[o];
}

extern "C" void kernel_launch(void* const* d_in, const int* in_sizes, int n_in,
                              void* d_out, int out_size, void* d_ws, size_t ws_size,
                              hipStream_t stream){
  const void* xct_r =d_in[0];
  const void* xwsi_r=d_in[1];
  const void* Wct =d_in[2];
  const void* bct =d_in[3];
  const void* Wwsi=d_in[4];
  const void* bwsi=d_in[5];
  const void* Watt=d_in[6];
  const void* Winv=d_in[7];
  const void* binv=d_in[8];
  const void* Wrr =d_in[9];
  const void* g1  =d_in[10];
  const void* be1 =d_in[11];
  const void* g2  =d_in[12];
  const void* be2 =d_in[13];
  const void* Wp1 =d_in[14];
  const void* Wp2 =d_in[16];
  const void* bp2 =d_in[17];
  float* ws=(float*)d_ws;
  float* x1=ws+X1o; float* pool=ws+POOLo; float* xw1=ws+XW1o;
  float* Wx=ws+WXo; float* WxT=ws+WXTo; float* Wix=ws+WIXo;
  float* att=ws+ATTo; float* kern=ws+KERNo; float* xw3=ws+XW3o;
  float* part=ws+PARTo;
  float* stat=ws+STATo; float* wf=ws+WFo;
  float* Wattf=ws+WATTFo; float* Winvf=ws+WINVFo;
  int* flag=(int*)(ws+FLAGo);
  bf16* bfb=(bf16*)(ws+BF16o);
  bf16* xctb=bfb+bXCT; bf16* xwsib=bfb+bXWSI;
  bf16* xatt=bfb+bXATT; bf16* y1=bfb+bY1; bf16* invb=bfb+bINV; bf16* xatt1=bfb+bXATT1;
  float* sum1=stat; float* sq1=stat+256; float* sum2=stat+512; float* sq2=stat+768;
  float* sc1=stat+1024; float* sh1=stat+1280; float* sc2=stat+1536; float* sh2=stat+1792;

  hipMemsetAsync(stat,0,4096,stream);
  k_detect<<<1,64,0,stream>>>((const unsigned short*)xct_r,flag);
  k_c2b   <<<12544,256,0,stream>>>(xct_r,xctb,3211264,flag);
  k_c2b   <<<18816,256,0,stream>>>(xwsi_r,xwsib,4816896,flag);
  k_c2f   <<<3733,256,0,stream>>>(Watt,Wattf,955500,flag);
  k_c2f   <<<113,256,0,stream>>>(Winv,Winvf,28812,flag);
  k_cvt   <<<461,256,0,stream>>>(Wct,bct,Wwsi,bwsi,Wrr,binv,Wp1,Wp2,bp2,wf,flag);
  k_pool  <<<294,256,0,stream>>>(xwsib,pool);
  k_xw1   <<<294,256,0,stream>>>(pool,wf,xw1);
  k_Wx    <<<813,256,0,stream>>>(Wattf,xw1,Wx);
  k_WxT   <<<1000,256,0,stream>>>(Wx,WxT);
  k_Winvx <<<25,256,0,stream>>>(Winvf,xw1,Wix);
  k_x1    <<<dim3(98,4,2),256,0,stream>>>(xctb,wf,x1);
  k_att   <<<dim3(16,8,8),256,0,stream>>>(x1,WxT,part);     // 1024 blocks, 4/CU
  k_sig   <<<2548,256,0,stream>>>(part,att);                // consumes part before k_kern/k_rr reuse it
  k_kern  <<<dim3(98,2),256,0,stream>>>(x1,Wix,wf,kern);
  k_rr    <<<dim3(28,12,2),128,0,stream>>>(xwsib,wf,xw3);   // 672 blocks, 2 waves each
  k_xatt  <<<50176,256,0,stream>>>(xctb,xw3,att,xatt);
  k_p1    <<<dim3(98,16,2),256,0,stream>>>(xatt,wf,y1);
  k_stats <<<dim3(8,256,2),256,0,stream>>>(y1,sum1,sq1);
  k_finstat<<<1,256,0,stream>>>(sum1,sq1,g1,be1,flag,sc1,sh1);
  k_bn1   <<<dim3(392,2),256,0,stream>>>(y1,sc1,sh1,xatt1);
  k_inv   <<<dim3(49,4,16),64,0,stream>>>(xatt1,kern,invb);
  k_stats <<<dim3(8,256,2),256,0,stream>>>(invb,sum2,sq2);
  k_finstat<<<1,256,0,stream>>>(sum2,sq2,g2,be2,flag,sc2,sh2);
  k_final <<<dim3(98,4,2),256,0,stream>>>(invb,xatt,wf,sc2,sh2,(float*)d_out);
}